// Round 1
// baseline (2307.677 us; speedup 1.0000x reference)
//
#include <hip/hip_runtime.h>
#include <stdint.h>

#define D_ 128
#define NB_ 20
#define TB_ 64

__device__ __forceinline__ float silu_f(float x) { return x / (1.0f + __expf(-x)); }

__device__ __forceinline__ float bf2f(unsigned short u) {
  return __uint_as_float(((unsigned int)u) << 16);
}
__device__ __forceinline__ unsigned short f2bf(float f) {
  unsigned int x = __float_as_uint(f);
  return (unsigned short)((x + 0x7fffu + ((x >> 16) & 1u)) >> 16);
}

template<typename ST> __device__ __forceinline__ float4 load4_st(const ST* p);
template<> __device__ __forceinline__ float4 load4_st<float>(const float* p) {
  return *(const float4*)p;
}
template<> __device__ __forceinline__ float4 load4_st<unsigned short>(const unsigned short* p) {
  ushort4 u = *(const ushort4*)p;
  return make_float4(bf2f(u.x), bf2f(u.y), bf2f(u.z), bf2f(u.w));
}
template<typename ST> __device__ __forceinline__ void store_st(ST* p, float v);
template<> __device__ __forceinline__ void store_st<float>(float* p, float v) { *p = v; }
template<> __device__ __forceinline__ void store_st<unsigned short>(unsigned short* p, float v) { *p = f2bf(v); }

// ---------------------------------------------------------------------------
// Fold the angle-MLP tail into W1's last 20 rows:
//   M = A2 @ W1c   (20 x 128),   b1p = b1 + ab2 @ W1c
__global__ void prep_kernel(const float* __restrict__ A2, const float* __restrict__ ab2,
                            const float* __restrict__ W1, const float* __restrict__ b1,
                            float* __restrict__ Mfold, float* __restrict__ b1p) {
  int tid = blockIdx.x * blockDim.x + threadIdx.x;
  if (tid >= 21 * D_) return;
  int r = tid >> 7, c = tid & (D_ - 1);
  if (r < NB_) {
    float acc = 0.f;
    for (int j = 0; j < NB_; ++j) acc += A2[r * NB_ + j] * W1[(2 * D_ + j) * D_ + c];
    Mfold[r * D_ + c] = acc;
  } else {
    float acc = b1[c];
    for (int j = 0; j < NB_; ++j) acc += ab2[j] * W1[(2 * D_ + j) * D_ + c];
    b1p[c] = acc;
  }
}

// ---------------------------------------------------------------------------
// P[e][c] = sum_k edge_attr[e][k] * W1[k][c]
// Q[e][c] = sum_k edge_attr[e][k] * W1[128+k][c]
// Tiled fp32 GEMM: 32 edges x 256 virtual cols per block.
template<typename ST>
__global__ __launch_bounds__(256) void pq_kernel(const float* __restrict__ edge_attr,
                                                 const float* __restrict__ W1,
                                                 ST* __restrict__ P, ST* __restrict__ Q, int E) {
  __shared__ float At[128][36];  // transposed A tile, padded
  const int tid = threadIdx.x;
  const int e_base = blockIdx.x * 32;
  {
    int el = tid >> 3;
    int e = e_base + el; if (e > E - 1) e = E - 1;
    int c0 = (tid & 7) * 16;
    const float4* src = (const float4*)(edge_attr + (size_t)e * D_ + c0);
#pragma unroll
    for (int i = 0; i < 4; ++i) {
      float4 v = src[i];
      At[c0 + i * 4 + 0][el] = v.x;
      At[c0 + i * 4 + 1][el] = v.y;
      At[c0 + i * 4 + 2][el] = v.z;
      At[c0 + i * 4 + 3][el] = v.w;
    }
  }
  __syncthreads();
  const int cg = tid & 31, eg = tid >> 5;
  const int e0 = eg * 4;       // 8 groups * 4 edges
  const int n0 = cg * 8;       // 32 groups * 8 cols (0..255)
  const float* Wbase = (n0 < 128) ? (W1 + n0) : (W1 + 128 * D_ + (n0 - 128));
  float acc[4][8];
#pragma unroll
  for (int i = 0; i < 4; ++i)
#pragma unroll
    for (int j = 0; j < 8; ++j) acc[i][j] = 0.f;
  for (int k = 0; k < 128; ++k) {
    float a[4];
    *(float4*)a = *(const float4*)&At[k][e0];
    float w[8];
    *(float4*)&w[0] = *(const float4*)(Wbase + k * D_);
    *(float4*)&w[4] = *(const float4*)(Wbase + k * D_ + 4);
#pragma unroll
    for (int i = 0; i < 4; ++i)
#pragma unroll
      for (int j = 0; j < 8; ++j) acc[i][j] += a[i] * w[j];
  }
  ST* Obase = (n0 < 128) ? (P + n0) : (Q + (n0 - 128));
#pragma unroll
  for (int i = 0; i < 4; ++i) {
    int e = e_base + e0 + i;
    if (e < E) {
      ST* orow = Obase + (size_t)e * D_;
#pragma unroll
      for (int j = 0; j < 8; ++j) store_st<ST>(orow + j, acc[i][j]);
    }
  }
}

// ---------------------------------------------------------------------------
// Per-triplet: g = silu(f@A1+ab1); u = P[eij]+Q[eik]+g@M+b1p; t = silu(u);
// m = t@W2 + b2; atomicAdd into delta[eij].
// One block = 64 triplets.
template<typename ST>
__global__ __launch_bounds__(256) void triplet_kernel(
    const int* __restrict__ tbe, const float* __restrict__ edge_vectors,
    const float* __restrict__ A1, const float* __restrict__ ab1,
    const float* __restrict__ Mfold, const float* __restrict__ b1p,
    const ST* __restrict__ P, const ST* __restrict__ Q,
    const float* __restrict__ W2, const float* __restrict__ b2,
    float* __restrict__ delta, int T_) {
  __shared__ float t_lds[D_][TB_];   // transposed activations (32 KB)
  __shared__ float g_lds[TB_][NB_];
  __shared__ int   eij_lds[TB_];
  __shared__ int   eik_lds[TB_];
  __shared__ float M_lds[NB_][D_];
  __shared__ float b1p_lds[D_];
  __shared__ float b2_lds[D_];
  const int tid = threadIdx.x;
  for (int i = tid; i < NB_ * D_; i += 256) M_lds[i >> 7][i & (D_ - 1)] = Mfold[i];
  if (tid < D_) { b1p_lds[tid] = b1p[tid]; b2_lds[tid] = b2[tid]; }

  const int jbase = blockIdx.x * TB_;
  const int j = tid >> 2;
  const int q = tid & 3;
  const int jj = jbase + j;

  // phase A0: geometry + angle basis (4 threads/triplet, 5 basis fns each)
  {
    int eij = 0, eik = 0;
    float lij = 1.f, lik = 1.f, cosv = 0.f;
    if (jj < T_) {
      eij = tbe[2 * jj]; eik = tbe[2 * jj + 1];
      const float* v1 = edge_vectors + 3 * (size_t)eij;
      const float* v2 = edge_vectors + 3 * (size_t)eik;
      float ax = v1[0], ay = v1[1], az = v1[2];
      float bx = v2[0], by = v2[1], bz = v2[2];
      // vec = -edge_vectors: sign cancels in both len and cos.
      lij = fmaxf(sqrtf(ax * ax + ay * ay + az * az), 1e-6f);
      lik = fmaxf(sqrtf(bx * bx + by * by + bz * bz), 1e-6f);
      cosv = (ax * bx + ay * by + az * bz) / (lij * lik);
      cosv = fminf(fmaxf(cosv, -1.f), 1.f);
    }
    if (q == 0) { eij_lds[j] = eij; eik_lds[j] = eik; }
#pragma unroll
    for (int kk = 0; kk < 5; ++kk) {
      int k = q * 5 + kk;
      float x = lij * A1[k] + lik * A1[NB_ + k] + cosv * A1[2 * NB_ + k] + ab1[k];
      g_lds[j][k] = silu_f(x);
    }
  }
  __syncthreads();

  // phase A1: u rows -> silu -> t_lds (transposed). thread: (triplet j, 32 chans)
  {
    const int c0 = q * 32;
    float g[NB_];
#pragma unroll
    for (int k = 0; k < NB_; ++k) g[k] = g_lds[j][k];
    const int eij = eij_lds[j], eik = eik_lds[j];
    const ST* prow = P + (size_t)eij * D_ + c0;
    const ST* qrow = Q + (size_t)eik * D_ + c0;
#pragma unroll
    for (int c4 = 0; c4 < 8; ++c4) {
      float4 pa = load4_st<ST>(prow + 4 * c4);
      float4 qa = load4_st<ST>(qrow + 4 * c4);
      int c = c0 + 4 * c4;
      float u0 = pa.x + qa.x + b1p_lds[c + 0];
      float u1 = pa.y + qa.y + b1p_lds[c + 1];
      float u2 = pa.z + qa.z + b1p_lds[c + 2];
      float u3 = pa.w + qa.w + b1p_lds[c + 3];
#pragma unroll
      for (int k = 0; k < NB_; ++k) {
        const float4 m4 = *(const float4*)&M_lds[k][c];
        u0 += g[k] * m4.x; u1 += g[k] * m4.y;
        u2 += g[k] * m4.z; u3 += g[k] * m4.w;
      }
      t_lds[c + 0][j] = silu_f(u0);
      t_lds[c + 1][j] = silu_f(u1);
      t_lds[c + 2][j] = silu_f(u2);
      t_lds[c + 3][j] = silu_f(u3);
    }
  }
  __syncthreads();

  // phase B: m = t^T @ W2 (64x128 @ 128x128), then atomic segment-sum.
  {
    const int cg = tid & 31, jg = tid >> 5;
    const int c0 = cg * 4, j0 = jg * 8;
    float acc[8][4];
#pragma unroll
    for (int i = 0; i < 8; ++i) { acc[i][0] = acc[i][1] = acc[i][2] = acc[i][3] = 0.f; }
    for (int k = 0; k < D_; ++k) {
      float w[4];
      *(float4*)w = *(const float4*)(W2 + k * D_ + c0);
      float tj[8];
      *(float4*)&tj[0] = *(const float4*)&t_lds[k][j0];
      *(float4*)&tj[4] = *(const float4*)&t_lds[k][j0 + 4];
#pragma unroll
      for (int i = 0; i < 8; ++i) {
#pragma unroll
        for (int l = 0; l < 4; ++l) acc[i][l] += tj[i] * w[l];
      }
    }
#pragma unroll
    for (int i = 0; i < 8; ++i) {
      int jl = j0 + i;
      if (jbase + jl < T_) {
        int e = eij_lds[jl];
        float* drow = delta + (size_t)e * D_ + c0;
#pragma unroll
        for (int l = 0; l < 4; ++l) atomicAdd(drow + l, acc[i][l] + b2_lds[c0 + l]);
      }
    }
  }
}

// ---------------------------------------------------------------------------
// In-place: out[e] = delta[e] @ Wu + bu  (row->row, so d_out can hold delta)
__global__ __launch_bounds__(256) void wu_kernel(float* __restrict__ io,
                                                 const float* __restrict__ Wu,
                                                 const float* __restrict__ bu, int E) {
  __shared__ float At[128][36];
  const int tid = threadIdx.x;
  const int e_base = blockIdx.x * 32;
  {
    int el = tid >> 3;
    int e = e_base + el; if (e > E - 1) e = E - 1;
    int c0 = (tid & 7) * 16;
    const float4* src = (const float4*)(io + (size_t)e * D_ + c0);
#pragma unroll
    for (int i = 0; i < 4; ++i) {
      float4 v = src[i];
      At[c0 + i * 4 + 0][el] = v.x;
      At[c0 + i * 4 + 1][el] = v.y;
      At[c0 + i * 4 + 2][el] = v.z;
      At[c0 + i * 4 + 3][el] = v.w;
    }
  }
  __syncthreads();
  const int cg = tid & 31, eg = tid >> 5;
  const int e0 = eg * 4, c0 = cg * 4;
  float acc[4][4];
#pragma unroll
  for (int i = 0; i < 4; ++i) { acc[i][0] = acc[i][1] = acc[i][2] = acc[i][3] = 0.f; }
  for (int k = 0; k < 128; ++k) {
    float a[4];
    *(float4*)a = *(const float4*)&At[k][e0];
    float w[4];
    *(float4*)w = *(const float4*)(Wu + k * D_ + c0);
#pragma unroll
    for (int i = 0; i < 4; ++i)
#pragma unroll
      for (int l = 0; l < 4; ++l) acc[i][l] += a[i] * w[l];
  }
#pragma unroll
  for (int i = 0; i < 4; ++i) {
    int e = e_base + e0 + i;
    if (e < E) {
      float4 r;
      r.x = acc[i][0] + bu[c0 + 0];
      r.y = acc[i][1] + bu[c0 + 1];
      r.z = acc[i][2] + bu[c0 + 2];
      r.w = acc[i][3] + bu[c0 + 3];
      *(float4*)(io + (size_t)e * D_ + c0) = r;
    }
  }
}

// ---------------------------------------------------------------------------
extern "C" void kernel_launch(void* const* d_in, const int* in_sizes, int n_in,
                              void* d_out, int out_size, void* d_ws, size_t ws_size,
                              hipStream_t stream) {
  const float* edge_attr    = (const float*)d_in[0];
  const int*   tbe          = (const int*)d_in[2];
  const float* edge_vectors = (const float*)d_in[3];
  const float* A1  = (const float*)d_in[4];
  const float* ab1 = (const float*)d_in[5];
  const float* A2  = (const float*)d_in[6];
  const float* ab2 = (const float*)d_in[7];
  const float* W1  = (const float*)d_in[8];
  const float* b1  = (const float*)d_in[9];
  const float* W2  = (const float*)d_in[10];
  const float* b2  = (const float*)d_in[11];
  const float* Wu  = (const float*)d_in[12];
  const float* bu  = (const float*)d_in[13];
  const int E = in_sizes[0] / D_;
  const int T = in_sizes[2] / 2;
  float* out = (float*)d_out;

  const size_t smallsz = (size_t)(NB_ * D_ + D_) * sizeof(float);
  const size_t need_f32 = (size_t)2 * E * D_ * sizeof(float) + smallsz;

  // delta accumulates directly in d_out (zeroed each call); wu_kernel is
  // in-place row->row so no extra buffer needed.
  hipMemsetAsync(d_out, 0, (size_t)E * D_ * sizeof(float), stream);

  const int prep_blocks = (21 * D_ + 255) / 256;
  const int pq_blocks = (E + 31) / 32;
  const int tr_blocks = (T + TB_ - 1) / TB_;

  if (ws_size >= need_f32) {
    float* P = (float*)d_ws;
    float* Q = P + (size_t)E * D_;
    float* Mfold = Q + (size_t)E * D_;
    float* b1p = Mfold + NB_ * D_;
    prep_kernel<<<prep_blocks, 256, 0, stream>>>(A2, ab2, W1, b1, Mfold, b1p);
    pq_kernel<float><<<pq_blocks, 256, 0, stream>>>(edge_attr, W1, P, Q, E);
    triplet_kernel<float><<<tr_blocks, 256, 0, stream>>>(
        tbe, edge_vectors, A1, ab1, Mfold, b1p, P, Q, W2, b2, out, T);
  } else {
    // bf16 fallback for small workspace (P/Q stored as bf16)
    unsigned short* P = (unsigned short*)d_ws;
    unsigned short* Q = P + (size_t)E * D_;
    float* Mfold = (float*)(Q + (size_t)E * D_);
    float* b1p = Mfold + NB_ * D_;
    prep_kernel<<<prep_blocks, 256, 0, stream>>>(A2, ab2, W1, b1, Mfold, b1p);
    pq_kernel<unsigned short><<<pq_blocks, 256, 0, stream>>>(edge_attr, W1, P, Q, E);
    triplet_kernel<unsigned short><<<tr_blocks, 256, 0, stream>>>(
        tbe, edge_vectors, A1, ab1, Mfold, b1p, P, Q, W2, b2, out, T);
  }
  wu_kernel<<<pq_blocks, 256, 0, stream>>>(out, Wu, bu, E);
}

// Round 2
// 984.141 us; speedup vs baseline: 2.3449x; 2.3449x over previous
//
#include <hip/hip_runtime.h>
#include <stdint.h>

#define D_ 128
#define NB_ 20
#define SCAN_B 1024

__device__ __forceinline__ float silu_f(float x) { return x / (1.0f + __expf(-x)); }

__device__ __forceinline__ float bf2f(unsigned short u) {
  return __uint_as_float(((unsigned int)u) << 16);
}
__device__ __forceinline__ unsigned short f2bf(float f) {
  unsigned int x = __float_as_uint(f);
  return (unsigned short)((x + 0x7fffu + ((x >> 16) & 1u)) >> 16);
}

// ---------------------------------------------------------------------------
// Fold angle-MLP tail into W1's last 20 rows: Mfold = A2@W1c, b1p = b1 + ab2@W1c
__global__ void prep_kernel(const float* __restrict__ A2, const float* __restrict__ ab2,
                            const float* __restrict__ W1, const float* __restrict__ b1,
                            float* __restrict__ Mfold, float* __restrict__ b1p) {
  int tid = blockIdx.x * blockDim.x + threadIdx.x;
  if (tid >= 21 * D_) return;
  int r = tid >> 7, c = tid & (D_ - 1);
  if (r < NB_) {
    float acc = 0.f;
    for (int j = 0; j < NB_; ++j) acc += A2[r * NB_ + j] * W1[(2 * D_ + j) * D_ + c];
    Mfold[r * D_ + c] = acc;
  } else {
    float acc = b1[c];
    for (int j = 0; j < NB_; ++j) acc += ab2[j] * W1[(2 * D_ + j) * D_ + c];
    b1p[c] = acc;
  }
}

// W2u = W2 @ Wu (128x128), c2 = b2 @ Wu (128)
__global__ void prep2_kernel(const float* __restrict__ W2, const float* __restrict__ Wu,
                             const float* __restrict__ b2,
                             float* __restrict__ W2u, float* __restrict__ c2) {
  int tid = blockIdx.x * blockDim.x + threadIdx.x;
  if (tid < D_ * D_) {
    int r = tid >> 7, c = tid & (D_ - 1);
    float acc = 0.f;
    for (int m = 0; m < D_; ++m) acc += W2[r * D_ + m] * Wu[m * D_ + c];
    W2u[tid] = acc;
  } else if (tid < D_ * D_ + D_) {
    int c = tid - D_ * D_;
    float acc = 0.f;
    for (int m = 0; m < D_; ++m) acc += b2[m] * Wu[m * D_ + c];
    c2[c] = acc;
  }
}

// ---------------------------------------------------------------------------
// P[e] = edge_attr[e] @ W1[0:128], Q[e] = edge_attr[e] @ W1[128:256]  (bf16 out)
__global__ __launch_bounds__(256) void pq_kernel(const float* __restrict__ edge_attr,
                                                 const float* __restrict__ W1,
                                                 unsigned short* __restrict__ P,
                                                 unsigned short* __restrict__ Q, int E) {
  __shared__ float At[128][36];
  const int tid = threadIdx.x;
  const int e_base = blockIdx.x * 32;
  {
    int el = tid >> 3;
    int e = e_base + el; if (e > E - 1) e = E - 1;
    int c0 = (tid & 7) * 16;
    const float4* src = (const float4*)(edge_attr + (size_t)e * D_ + c0);
#pragma unroll
    for (int i = 0; i < 4; ++i) {
      float4 v = src[i];
      At[c0 + i * 4 + 0][el] = v.x;
      At[c0 + i * 4 + 1][el] = v.y;
      At[c0 + i * 4 + 2][el] = v.z;
      At[c0 + i * 4 + 3][el] = v.w;
    }
  }
  __syncthreads();
  const int cg = tid & 31, eg = tid >> 5;
  const int e0 = eg * 4;
  const int n0 = cg * 8;
  const float* Wbase = (n0 < 128) ? (W1 + n0) : (W1 + 128 * D_ + (n0 - 128));
  float acc[4][8];
#pragma unroll
  for (int i = 0; i < 4; ++i)
#pragma unroll
    for (int j = 0; j < 8; ++j) acc[i][j] = 0.f;
  for (int k = 0; k < 128; ++k) {
    float a[4];
    *(float4*)a = *(const float4*)&At[k][e0];
    float w[8];
    *(float4*)&w[0] = *(const float4*)(Wbase + k * D_);
    *(float4*)&w[4] = *(const float4*)(Wbase + k * D_ + 4);
#pragma unroll
    for (int i = 0; i < 4; ++i)
#pragma unroll
      for (int j = 0; j < 8; ++j) acc[i][j] += a[i] * w[j];
  }
  unsigned short* Obase = (n0 < 128) ? (P + n0) : (Q + (n0 - 128));
#pragma unroll
  for (int i = 0; i < 4; ++i) {
    int e = e_base + e0 + i;
    if (e < E) {
      unsigned short* orow = Obase + (size_t)e * D_;
#pragma unroll
      for (int j = 0; j < 8; ++j) orow[j] = f2bf(acc[i][j]);
    }
  }
}

// ---------------------------------------------------------------------------
// Counting sort of triplets by e_ij
__global__ void hist_kernel(const int* __restrict__ tbe, int* __restrict__ cnt, int T_) {
  int t = blockIdx.x * blockDim.x + threadIdx.x;
  if (t < T_) atomicAdd(&cnt[tbe[2 * t]], 1);
}

__global__ __launch_bounds__(SCAN_B) void scan1_kernel(const int* __restrict__ cnt,
                                                       int* __restrict__ pre,
                                                       int* __restrict__ bsum, int E) {
  __shared__ int lds[SCAN_B];
  int tid = threadIdx.x, i = blockIdx.x * SCAN_B + tid;
  int v = (i < E) ? cnt[i] : 0;
  lds[tid] = v;
  __syncthreads();
  for (int d = 1; d < SCAN_B; d <<= 1) {
    int add = (tid >= d) ? lds[tid - d] : 0;
    __syncthreads();
    lds[tid] += add;
    __syncthreads();
  }
  if (i < E) pre[i] = lds[tid] - v;
  if (tid == SCAN_B - 1) bsum[blockIdx.x] = lds[tid];
}

__global__ void scan2_kernel(int* __restrict__ bsum, int nb) {
  __shared__ int lds[256];
  int tid = threadIdx.x;
  int v = (tid < nb) ? bsum[tid] : 0;
  lds[tid] = v;
  __syncthreads();
  for (int d = 1; d < 256; d <<= 1) {
    int add = (tid >= d) ? lds[tid - d] : 0;
    __syncthreads();
    lds[tid] += add;
    __syncthreads();
  }
  if (tid < nb) bsum[tid] = lds[tid] - v;
}

__global__ __launch_bounds__(SCAN_B) void scan3_kernel(const int* __restrict__ pre,
                                                       const int* __restrict__ bsum,
                                                       int* __restrict__ offs,
                                                       int* __restrict__ cursor, int E, int T_) {
  int i = blockIdx.x * SCAN_B + threadIdx.x;
  if (i < E) {
    int o = pre[i] + bsum[blockIdx.x];
    offs[i] = o;
    cursor[i] = o;
  }
  if (i == 0) offs[E] = T_;
}

__global__ void scatter_kernel(const int* __restrict__ tbe, int* __restrict__ cursor,
                               int* __restrict__ seik, int T_) {
  int t = blockIdx.x * blockDim.x + threadIdx.x;
  if (t < T_) {
    int2 v = ((const int2*)tbe)[t];
    int pos = atomicAdd(&cursor[v.x], 1);
    seik[pos] = v.y;
  }
}

// ---------------------------------------------------------------------------
// One wave per edge segment: s[e] = sum_t silu(P[e] + Q[eik] + g@M + b1p)
// Lane handles channels 2*lane, 2*lane+1. No LDS, no atomics.
__global__ __launch_bounds__(256) void seg_kernel(
    const int* __restrict__ offs, const int* __restrict__ seik,
    const float* __restrict__ edge_vectors,
    const float* __restrict__ A1, const float* __restrict__ ab1,
    const float* __restrict__ Mfold, const float* __restrict__ b1p,
    const unsigned short* __restrict__ P, const unsigned short* __restrict__ Q,
    float* __restrict__ s_out, int E) {
  const int lane = threadIdx.x & 63;
  const int wid = (blockIdx.x * blockDim.x + threadIdx.x) >> 6;
  const int nw = (gridDim.x * blockDim.x) >> 6;

  float2 m[NB_];
#pragma unroll
  for (int k = 0; k < NB_; ++k) m[k] = *(const float2*)(Mfold + k * D_ + 2 * lane);
  const float2 bb = *(const float2*)(b1p + 2 * lane);
  float a0 = 0.f, a1 = 0.f, a2 = 0.f, ab = 0.f;
  if (lane < NB_) {
    a0 = A1[lane]; a1 = A1[NB_ + lane]; a2 = A1[2 * NB_ + lane]; ab = ab1[lane];
  }

  for (int e = wid; e < E; e += nw) {
    int o0 = offs[e], o1 = offs[e + 1];
    float acc0 = 0.f, acc1 = 0.f;
    if (o1 > o0) {
      const float* vj = edge_vectors + 3 * (size_t)e;
      float jx = vj[0], jy = vj[1], jz = vj[2];
      float lij = fmaxf(sqrtf(jx * jx + jy * jy + jz * jz), 1e-6f);
      ushort2 pp = *(const ushort2*)(P + (size_t)e * D_ + 2 * lane);
      float base0 = bf2f(pp.x) + bb.x;
      float base1 = bf2f(pp.y) + bb.y;
      for (int t = o0; t < o1; ++t) {
        int eik = seik[t];
        const float* vk = edge_vectors + 3 * (size_t)eik;
        float kx = vk[0], ky = vk[1], kz = vk[2];
        float lik = fmaxf(sqrtf(kx * kx + ky * ky + kz * kz), 1e-6f);
        float cosv = (jx * kx + jy * ky + jz * kz) / (lij * lik);
        cosv = fminf(fmaxf(cosv, -1.f), 1.f);
        float g = silu_f(lij * a0 + lik * a1 + cosv * a2 + ab);
        ushort2 qq = *(const ushort2*)(Q + (size_t)eik * D_ + 2 * lane);
        float u0 = base0 + bf2f(qq.x);
        float u1 = base1 + bf2f(qq.y);
#pragma unroll
        for (int k = 0; k < NB_; ++k) {
          float gk = __shfl(g, k, 64);
          u0 += gk * m[k].x;
          u1 += gk * m[k].y;
        }
        acc0 += silu_f(u0);
        acc1 += silu_f(u1);
      }
    }
    *(float2*)(s_out + (size_t)e * D_ + 2 * lane) = make_float2(acc0, acc1);
  }
}

// ---------------------------------------------------------------------------
// In-place: out[e] = s[e] @ W2u + cnt[e]*c2 + bu
__global__ __launch_bounds__(256) void out_kernel(float* __restrict__ io,
                                                  const float* __restrict__ W2u,
                                                  const float* __restrict__ c2,
                                                  const float* __restrict__ bu,
                                                  const int* __restrict__ cnt, int E) {
  __shared__ float At[128][36];
  const int tid = threadIdx.x;
  const int e_base = blockIdx.x * 32;
  {
    int el = tid >> 3;
    int e = e_base + el; if (e > E - 1) e = E - 1;
    int c0 = (tid & 7) * 16;
    const float4* src = (const float4*)(io + (size_t)e * D_ + c0);
#pragma unroll
    for (int i = 0; i < 4; ++i) {
      float4 v = src[i];
      At[c0 + i * 4 + 0][el] = v.x;
      At[c0 + i * 4 + 1][el] = v.y;
      At[c0 + i * 4 + 2][el] = v.z;
      At[c0 + i * 4 + 3][el] = v.w;
    }
  }
  __syncthreads();
  const int cg = tid & 31, eg = tid >> 5;
  const int e0 = eg * 4, c0 = cg * 4;
  float acc[4][4];
#pragma unroll
  for (int i = 0; i < 4; ++i) { acc[i][0] = acc[i][1] = acc[i][2] = acc[i][3] = 0.f; }
  for (int k = 0; k < 128; ++k) {
    float a[4];
    *(float4*)a = *(const float4*)&At[k][e0];
    float w[4];
    *(float4*)w = *(const float4*)(W2u + k * D_ + c0);
#pragma unroll
    for (int i = 0; i < 4; ++i)
#pragma unroll
      for (int l = 0; l < 4; ++l) acc[i][l] += a[i] * w[l];
  }
#pragma unroll
  for (int i = 0; i < 4; ++i) {
    int e = e_base + e0 + i;
    if (e < E) {
      float nf = (float)cnt[e];
      float4 r;
      r.x = acc[i][0] + nf * c2[c0 + 0] + bu[c0 + 0];
      r.y = acc[i][1] + nf * c2[c0 + 1] + bu[c0 + 1];
      r.z = acc[i][2] + nf * c2[c0 + 2] + bu[c0 + 2];
      r.w = acc[i][3] + nf * c2[c0 + 3] + bu[c0 + 3];
      *(float4*)(io + (size_t)e * D_ + c0) = r;
    }
  }
}

// ---------------------------------------------------------------------------
extern "C" void kernel_launch(void* const* d_in, const int* in_sizes, int n_in,
                              void* d_out, int out_size, void* d_ws, size_t ws_size,
                              hipStream_t stream) {
  const float* edge_attr    = (const float*)d_in[0];
  const int*   tbe          = (const int*)d_in[2];
  const float* edge_vectors = (const float*)d_in[3];
  const float* A1  = (const float*)d_in[4];
  const float* ab1 = (const float*)d_in[5];
  const float* A2  = (const float*)d_in[6];
  const float* ab2 = (const float*)d_in[7];
  const float* W1  = (const float*)d_in[8];
  const float* b1  = (const float*)d_in[9];
  const float* W2  = (const float*)d_in[10];
  const float* b2  = (const float*)d_in[11];
  const float* Wu  = (const float*)d_in[12];
  const float* bu  = (const float*)d_in[13];
  const int E = in_sizes[0] / D_;
  const int T = in_sizes[2] / 2;
  float* out = (float*)d_out;

  // workspace carve (256B aligned regions)
  char* w = (char*)d_ws;
  auto carve = [&](size_t bytes) -> char* {
    char* p = w;
    w += (bytes + 255) & ~(size_t)255;
    return p;
  };
  unsigned short* P = (unsigned short*)carve((size_t)E * D_ * 2);
  unsigned short* Q = (unsigned short*)carve((size_t)E * D_ * 2);
  int* seik   = (int*)carve((size_t)T * 4);
  int* cnt    = (int*)carve((size_t)E * 4);
  int* pre    = (int*)carve((size_t)E * 4);
  int* offs   = (int*)carve((size_t)(E + 1) * 4);
  int* cursor = (int*)carve((size_t)E * 4);
  int* bsum   = (int*)carve(1024 * 4);
  float* Mfold = (float*)carve(NB_ * D_ * 4);
  float* b1p   = (float*)carve(D_ * 4);
  float* W2u   = (float*)carve(D_ * D_ * 4);
  float* c2    = (float*)carve(D_ * 4);

  const int nb_scan = (E + SCAN_B - 1) / SCAN_B;   // 196 for E=200000 (<=256 req)

  hipMemsetAsync(cnt, 0, (size_t)E * 4, stream);

  prep_kernel<<<(21 * D_ + 255) / 256, 256, 0, stream>>>(A2, ab2, W1, b1, Mfold, b1p);
  prep2_kernel<<<(D_ * D_ + D_ + 255) / 256, 256, 0, stream>>>(W2, Wu, b2, W2u, c2);
  pq_kernel<<<(E + 31) / 32, 256, 0, stream>>>(edge_attr, W1, P, Q, E);

  hist_kernel<<<(T + 255) / 256, 256, 0, stream>>>(tbe, cnt, T);
  scan1_kernel<<<nb_scan, SCAN_B, 0, stream>>>(cnt, pre, bsum, E);
  scan2_kernel<<<1, 256, 0, stream>>>(bsum, nb_scan);
  scan3_kernel<<<nb_scan, SCAN_B, 0, stream>>>(pre, bsum, offs, cursor, E, T);
  scatter_kernel<<<(T + 255) / 256, 256, 0, stream>>>(tbe, cursor, seik, T);

  seg_kernel<<<2048, 256, 0, stream>>>(offs, seik, edge_vectors, A1, ab1,
                                       Mfold, b1p, P, Q, out, E);
  out_kernel<<<(E + 31) / 32, 256, 0, stream>>>(out, W2u, c2, bu, cnt, E);
}

// Round 3
// 825.904 us; speedup vs baseline: 2.7941x; 1.1916x over previous
//
#include <hip/hip_runtime.h>
#include <stdint.h>

#define D_ 128
#define NB_ 20
#define SCAN_B 1024

typedef __bf16 bf16x8 __attribute__((ext_vector_type(8)));
typedef float f32x4 __attribute__((ext_vector_type(4)));

__device__ __forceinline__ float silu_f(float x) { return x / (1.0f + __expf(-x)); }

__device__ __forceinline__ float bf2f(unsigned short u) {
  return __uint_as_float(((unsigned int)u) << 16);
}
__device__ __forceinline__ unsigned short f2bf(float f) {
  unsigned int x = __float_as_uint(f);
  return (unsigned short)((x + 0x7fffu + ((x >> 16) & 1u)) >> 16);
}

// ---------------------------------------------------------------------------
// One prep kernel, three ranges:
//  [0, 2688):          Mfold = A2@W1c (20x128), b1p = b1 + ab2@W1c
//  [2688, 19200):      W2u = W2@Wu (128x128), c2 = b2@Wu
//  [19200, 51968):     W1T bf16, B-fragment friendly: W1T[half*128+n][k] = W1[half*128+k][n]
__global__ __launch_bounds__(256) void prep_kernel(
    const float* __restrict__ A2, const float* __restrict__ ab2,
    const float* __restrict__ W1, const float* __restrict__ b1,
    const float* __restrict__ W2, const float* __restrict__ Wu,
    const float* __restrict__ b2,
    float* __restrict__ Mfold, float* __restrict__ b1p,
    float* __restrict__ W2u, float* __restrict__ c2,
    unsigned short* __restrict__ W1T) {
  int tid = blockIdx.x * blockDim.x + threadIdx.x;
  if (tid < 21 * D_) {
    int r = tid >> 7, c = tid & (D_ - 1);
    if (r < NB_) {
      float acc = 0.f;
      for (int j = 0; j < NB_; ++j) acc += A2[r * NB_ + j] * W1[(2 * D_ + j) * D_ + c];
      Mfold[r * D_ + c] = acc;
    } else {
      float acc = b1[c];
      for (int j = 0; j < NB_; ++j) acc += ab2[j] * W1[(2 * D_ + j) * D_ + c];
      b1p[c] = acc;
    }
  } else if (tid < 2688 + 16512) {
    int i = tid - 2688;
    if (i < D_ * D_) {
      int r = i >> 7, c = i & (D_ - 1);
      float acc = 0.f;
      for (int m = 0; m < D_; ++m) acc += W2[r * D_ + m] * Wu[m * D_ + c];
      W2u[i] = acc;
    } else {
      int c = i - D_ * D_;
      float acc = 0.f;
      for (int m = 0; m < D_; ++m) acc += b2[m] * Wu[m * D_ + c];
      c2[c] = acc;
    }
  } else if (tid < 19200 + 32768) {
    int i = tid - 19200;
    int r = i >> 7, k = i & 127;       // r = half*128 + n
    int half = r >> 7, n = r & 127;
    W1T[i] = f2bf(W1[(size_t)(half * 128 + k) * D_ + n]);
  }
}

// ---------------------------------------------------------------------------
// MFMA pq: P = edge_attr @ W1[0:128], Q = edge_attr @ W1[128:256], bf16 out.
// One wave = 16 edges. A-frag: lane holds A[m=lane&15][k=(lane>>4)*8+j].
// B-frag: lane holds B[k=(lane>>4)*8+j][n=lane&15] = W1T[half*128+n][k..k+7].
// C/D: col=lane&15, row=(lane>>4)*4+reg.
__global__ __launch_bounds__(256) void pq_mfma(const float* __restrict__ edge_attr,
                                               const unsigned short* __restrict__ W1T,
                                               unsigned short* __restrict__ P,
                                               unsigned short* __restrict__ Q, int E) {
  const int lane = threadIdx.x & 63;
  const int wave = threadIdx.x >> 6;
  const int e0 = (blockIdx.x * 4 + wave) * 16;
  if (e0 >= E) return;
  const int row = lane & 15;
  const int quad = lane >> 4;
  int e = e0 + row; if (e >= E) e = E - 1;

  union { bf16x8 v; unsigned short u[8]; } afr[4];
  const float* arow = edge_attr + (size_t)e * D_ + quad * 8;
#pragma unroll
  for (int kt = 0; kt < 4; ++kt) {
    float4 f0 = *(const float4*)(arow + kt * 32);
    float4 f1 = *(const float4*)(arow + kt * 32 + 4);
    afr[kt].u[0] = f2bf(f0.x); afr[kt].u[1] = f2bf(f0.y);
    afr[kt].u[2] = f2bf(f0.z); afr[kt].u[3] = f2bf(f0.w);
    afr[kt].u[4] = f2bf(f1.x); afr[kt].u[5] = f2bf(f1.y);
    afr[kt].u[6] = f2bf(f1.z); afr[kt].u[7] = f2bf(f1.w);
  }
#pragma unroll
  for (int half = 0; half < 2; ++half) {
    unsigned short* Obase = half ? Q : P;
#pragma unroll
    for (int nt = 0; nt < 8; ++nt) {
      const unsigned short* wrow =
          W1T + ((size_t)(half * 128 + nt * 16 + row)) * 128 + quad * 8;
      f32x4 acc = {0.f, 0.f, 0.f, 0.f};
#pragma unroll
      for (int kt = 0; kt < 4; ++kt) {
        bf16x8 bfr = *(const bf16x8*)(wrow + kt * 32);
        acc = __builtin_amdgcn_mfma_f32_16x16x32_bf16(afr[kt].v, bfr, acc, 0, 0, 0);
      }
      int n = nt * 16 + row;
#pragma unroll
      for (int i = 0; i < 4; ++i) {
        int er = e0 + quad * 4 + i;
        if (er < E) Obase[(size_t)er * D_ + n] = f2bf(acc[i]);
      }
    }
  }
}

// ---------------------------------------------------------------------------
// Counting sort by e_ij
__global__ void hist_kernel(const int* __restrict__ tbe, int* __restrict__ cnt, int T_) {
  int t = blockIdx.x * blockDim.x + threadIdx.x;
  if (t < T_) atomicAdd(&cnt[((const int2*)tbe)[t].x], 1);
}

__global__ __launch_bounds__(SCAN_B) void scan1_kernel(const int* __restrict__ cnt,
                                                       int* __restrict__ pre,
                                                       int* __restrict__ bsum, int E) {
  __shared__ int lds[SCAN_B];
  int tid = threadIdx.x, i = blockIdx.x * SCAN_B + tid;
  int v = (i < E) ? cnt[i] : 0;
  lds[tid] = v;
  __syncthreads();
  for (int d = 1; d < SCAN_B; d <<= 1) {
    int add = (tid >= d) ? lds[tid - d] : 0;
    __syncthreads();
    lds[tid] += add;
    __syncthreads();
  }
  if (i < E) pre[i] = lds[tid] - v;
  if (tid == SCAN_B - 1) bsum[blockIdx.x] = lds[tid];
}

__global__ void scan2_kernel(int* __restrict__ bsum, int nb) {
  __shared__ int lds[256];
  int tid = threadIdx.x;
  int v = (tid < nb) ? bsum[tid] : 0;
  lds[tid] = v;
  __syncthreads();
  for (int d = 1; d < 256; d <<= 1) {
    int add = (tid >= d) ? lds[tid - d] : 0;
    __syncthreads();
    lds[tid] += add;
    __syncthreads();
  }
  if (tid < nb) bsum[tid] = lds[tid] - v;
}

__global__ __launch_bounds__(SCAN_B) void scan3_kernel(const int* __restrict__ pre,
                                                       const int* __restrict__ bsum,
                                                       int* __restrict__ offs,
                                                       int* __restrict__ cursor, int E, int T_) {
  int i = blockIdx.x * SCAN_B + threadIdx.x;
  if (i < E) {
    int o = pre[i] + bsum[blockIdx.x];
    offs[i] = o;
    cursor[i] = o;
  }
  if (i == 0) offs[E] = T_;
}

// Scatter + fused geometry: writes seik[pos] and g[pos][20] (fp32).
__global__ void scatter_kernel(const int* __restrict__ tbe, int* __restrict__ cursor,
                               const float* __restrict__ edge_vectors,
                               const float* __restrict__ A1, const float* __restrict__ ab1,
                               int* __restrict__ seik, float* __restrict__ gT, int T_) {
  int t = blockIdx.x * blockDim.x + threadIdx.x;
  if (t >= T_) return;
  int2 v = ((const int2*)tbe)[t];
  int pos = atomicAdd(&cursor[v.x], 1);
  seik[pos] = v.y;
  const float* vj = edge_vectors + 3 * (size_t)v.x;
  const float* vk = edge_vectors + 3 * (size_t)v.y;
  float jx = vj[0], jy = vj[1], jz = vj[2];
  float kx = vk[0], ky = vk[1], kz = vk[2];
  // vec = -edge_vectors: signs cancel in len and cos.
  float lij = fmaxf(sqrtf(jx * jx + jy * jy + jz * jz), 1e-6f);
  float lik = fmaxf(sqrtf(kx * kx + ky * ky + kz * kz), 1e-6f);
  float cosv = (jx * kx + jy * ky + jz * kz) / (lij * lik);
  cosv = fminf(fmaxf(cosv, -1.f), 1.f);
  float* grow = gT + (size_t)pos * NB_;
#pragma unroll
  for (int k = 0; k < NB_; ++k)
    grow[k] = silu_f(lij * A1[k] + lik * A1[NB_ + k] + cosv * A1[2 * NB_ + k] + ab1[k]);
}

// ---------------------------------------------------------------------------
// One wave per edge segment: s[e] = sum_t silu(P[e] + Q[eik_t] + g_t@M + b1p).
// g broadcast via v_readlane (VALU), seik/g software-pipelined.
__global__ __launch_bounds__(256) void seg_kernel(
    const int* __restrict__ offs, const int* __restrict__ seik,
    const float* __restrict__ gT,
    const float* __restrict__ Mfold, const float* __restrict__ b1p,
    const unsigned short* __restrict__ P, const unsigned short* __restrict__ Q,
    float* __restrict__ s_out, int E) {
  const int lane = threadIdx.x & 63;
  const int wid = (blockIdx.x * blockDim.x + threadIdx.x) >> 6;
  const int nw = (gridDim.x * blockDim.x) >> 6;

  float2 m[NB_];
#pragma unroll
  for (int k = 0; k < NB_; ++k) m[k] = *(const float2*)(Mfold + k * D_ + 2 * lane);
  const float2 bb = *(const float2*)(b1p + 2 * lane);
  const int gidx = (lane < NB_) ? lane : (NB_ - 1);

  for (int e = wid; e < E; e += nw) {
    int o0 = offs[e], o1 = offs[e + 1];
    float acc0 = 0.f, acc1 = 0.f;
    if (o1 > o0) {
      ushort2 pp = *(const ushort2*)(P + (size_t)e * D_ + 2 * lane);
      float base0 = bf2f(pp.x) + bb.x;
      float base1 = bf2f(pp.y) + bb.y;
      int eik = seik[o0];
      float gl = gT[(size_t)o0 * NB_ + gidx];
      for (int t = o0; t < o1; ++t) {
        int tn = (t + 1 < o1) ? (t + 1) : t;
        int eik_n = seik[tn];
        float gl_n = gT[(size_t)tn * NB_ + gidx];
        ushort2 qq = *(const ushort2*)(Q + (size_t)eik * D_ + 2 * lane);
        float u0 = base0 + bf2f(qq.x);
        float u1 = base1 + bf2f(qq.y);
#pragma unroll
        for (int k = 0; k < NB_; ++k) {
          float gk = __uint_as_float(__builtin_amdgcn_readlane(__float_as_uint(gl), k));
          u0 = fmaf(gk, m[k].x, u0);
          u1 = fmaf(gk, m[k].y, u1);
        }
        acc0 += silu_f(u0);
        acc1 += silu_f(u1);
        eik = eik_n;
        gl = gl_n;
      }
    }
    *(float2*)(s_out + (size_t)e * D_ + 2 * lane) = make_float2(acc0, acc1);
  }
}

// ---------------------------------------------------------------------------
// In-place: out[e] = s[e] @ W2u + cnt[e]*c2 + bu  (fp32 for precision)
__global__ __launch_bounds__(256) void out_kernel(float* __restrict__ io,
                                                  const float* __restrict__ W2u,
                                                  const float* __restrict__ c2,
                                                  const float* __restrict__ bu,
                                                  const int* __restrict__ cnt, int E) {
  __shared__ float At[128][36];
  const int tid = threadIdx.x;
  const int e_base = blockIdx.x * 32;
  {
    int el = tid >> 3;
    int e = e_base + el; if (e > E - 1) e = E - 1;
    int c0 = (tid & 7) * 16;
    const float4* src = (const float4*)(io + (size_t)e * D_ + c0);
#pragma unroll
    for (int i = 0; i < 4; ++i) {
      float4 v = src[i];
      At[c0 + i * 4 + 0][el] = v.x;
      At[c0 + i * 4 + 1][el] = v.y;
      At[c0 + i * 4 + 2][el] = v.z;
      At[c0 + i * 4 + 3][el] = v.w;
    }
  }
  __syncthreads();
  const int cg = tid & 31, eg = tid >> 5;
  const int e0 = eg * 4, c0 = cg * 4;
  float acc[4][4];
#pragma unroll
  for (int i = 0; i < 4; ++i) { acc[i][0] = acc[i][1] = acc[i][2] = acc[i][3] = 0.f; }
  for (int k = 0; k < 128; ++k) {
    float a[4];
    *(float4*)a = *(const float4*)&At[k][e0];
    float w[4];
    *(float4*)w = *(const float4*)(W2u + k * D_ + c0);
#pragma unroll
    for (int i = 0; i < 4; ++i)
#pragma unroll
      for (int l = 0; l < 4; ++l) acc[i][l] += a[i] * w[l];
  }
#pragma unroll
  for (int i = 0; i < 4; ++i) {
    int e = e_base + e0 + i;
    if (e < E) {
      float nf = (float)cnt[e];
      float4 r;
      r.x = acc[i][0] + nf * c2[c0 + 0] + bu[c0 + 0];
      r.y = acc[i][1] + nf * c2[c0 + 1] + bu[c0 + 1];
      r.z = acc[i][2] + nf * c2[c0 + 2] + bu[c0 + 2];
      r.w = acc[i][3] + nf * c2[c0 + 3] + bu[c0 + 3];
      *(float4*)(io + (size_t)e * D_ + c0) = r;
    }
  }
}

// ---------------------------------------------------------------------------
extern "C" void kernel_launch(void* const* d_in, const int* in_sizes, int n_in,
                              void* d_out, int out_size, void* d_ws, size_t ws_size,
                              hipStream_t stream) {
  const float* edge_attr    = (const float*)d_in[0];
  const int*   tbe          = (const int*)d_in[2];
  const float* edge_vectors = (const float*)d_in[3];
  const float* A1  = (const float*)d_in[4];
  const float* ab1 = (const float*)d_in[5];
  const float* A2  = (const float*)d_in[6];
  const float* ab2 = (const float*)d_in[7];
  const float* W1  = (const float*)d_in[8];
  const float* b1  = (const float*)d_in[9];
  const float* W2  = (const float*)d_in[10];
  const float* b2  = (const float*)d_in[11];
  const float* Wu  = (const float*)d_in[12];
  const float* bu  = (const float*)d_in[13];
  const int E = in_sizes[0] / D_;
  const int T = in_sizes[2] / 2;
  float* out = (float*)d_out;

  char* w = (char*)d_ws;
  auto carve = [&](size_t bytes) -> char* {
    char* p = w;
    w += (bytes + 255) & ~(size_t)255;
    return p;
  };
  unsigned short* P = (unsigned short*)carve((size_t)E * D_ * 2);
  unsigned short* Q = (unsigned short*)carve((size_t)E * D_ * 2);
  float* gT   = (float*)carve((size_t)T * NB_ * 4);
  int* seik   = (int*)carve((size_t)T * 4);
  int* cnt    = (int*)carve((size_t)E * 4);
  int* pre    = (int*)carve((size_t)E * 4);
  int* offs   = (int*)carve((size_t)(E + 1) * 4);
  int* cursor = (int*)carve((size_t)E * 4);
  int* bsum   = (int*)carve(1024 * 4);
  float* Mfold = (float*)carve(NB_ * D_ * 4);
  float* b1p   = (float*)carve(D_ * 4);
  float* W2u   = (float*)carve(D_ * D_ * 4);
  float* c2    = (float*)carve(D_ * 4);
  unsigned short* W1T = (unsigned short*)carve(256 * 128 * 2);

  const int nb_scan = (E + SCAN_B - 1) / SCAN_B;

  hipMemsetAsync(cnt, 0, (size_t)E * 4, stream);

  prep_kernel<<<(51968 + 255) / 256, 256, 0, stream>>>(A2, ab2, W1, b1, W2, Wu, b2,
                                                       Mfold, b1p, W2u, c2, W1T);
  pq_mfma<<<(E + 63) / 64, 256, 0, stream>>>(edge_attr, W1T, P, Q, E);

  hist_kernel<<<(T + 255) / 256, 256, 0, stream>>>(tbe, cnt, T);
  scan1_kernel<<<nb_scan, SCAN_B, 0, stream>>>(cnt, pre, bsum, E);
  scan2_kernel<<<1, 256, 0, stream>>>(bsum, nb_scan);
  scan3_kernel<<<nb_scan, SCAN_B, 0, stream>>>(pre, bsum, offs, cursor, E, T);
  scatter_kernel<<<(T + 255) / 256, 256, 0, stream>>>(tbe, cursor, edge_vectors,
                                                      A1, ab1, seik, gT, T);

  seg_kernel<<<2048, 256, 0, stream>>>(offs, seik, gT, Mfold, b1p, P, Q, out, E);
  out_kernel<<<(E + 31) / 32, 256, 0, stream>>>(out, W2u, c2, bu, cnt, E);
}

// Round 4
// 747.180 us; speedup vs baseline: 3.0885x; 1.1054x over previous
//
#include <hip/hip_runtime.h>
#include <stdint.h>

#define D_ 128
#define NB_ 20
#define SCAN_B 1024

typedef __bf16 bf16x8 __attribute__((ext_vector_type(8)));
typedef float f32x4 __attribute__((ext_vector_type(4)));
typedef float f32x2 __attribute__((ext_vector_type(2)));

__device__ __forceinline__ float silu_f(float x) { return x / (1.0f + __expf(-x)); }
__device__ __forceinline__ f32x2 silu2(f32x2 x) {
  return (f32x2){silu_f(x.x), silu_f(x.y)};
}
__device__ __forceinline__ f32x2 fsplat(float x) { return (f32x2){x, x}; }

__device__ __forceinline__ float bf2f(unsigned short u) {
  return __uint_as_float(((unsigned int)u) << 16);
}
__device__ __forceinline__ unsigned short f2bf(float f) {
  unsigned int x = __float_as_uint(f);
  return (unsigned short)((x + 0x7fffu + ((x >> 16) & 1u)) >> 16);
}

// ---------------------------------------------------------------------------
// prep ranges:
//  [0, 2688):           Mfold = A2@W1c (20x128), b1p = b1 + ab2@W1c
//  [2688, 19072):       W2uT bf16: W2uT[n*128+k] = (W2@Wu)[k][n]
//  [19072, 19200):      c2 = b2 @ Wu
//  [19200, 51968):      W1T bf16: W1T[half*128+n][k] = W1[half*128+k][n]
__global__ __launch_bounds__(256) void prep_kernel(
    const float* __restrict__ A2, const float* __restrict__ ab2,
    const float* __restrict__ W1, const float* __restrict__ b1,
    const float* __restrict__ W2, const float* __restrict__ Wu,
    const float* __restrict__ b2,
    float* __restrict__ Mfold, float* __restrict__ b1p,
    unsigned short* __restrict__ W2uT, float* __restrict__ c2,
    unsigned short* __restrict__ W1T) {
  int tid = blockIdx.x * blockDim.x + threadIdx.x;
  if (tid < 21 * D_) {
    int r = tid >> 7, c = tid & (D_ - 1);
    if (r < NB_) {
      float acc = 0.f;
      for (int j = 0; j < NB_; ++j) acc += A2[r * NB_ + j] * W1[(2 * D_ + j) * D_ + c];
      Mfold[r * D_ + c] = acc;
    } else {
      float acc = b1[c];
      for (int j = 0; j < NB_; ++j) acc += ab2[j] * W1[(2 * D_ + j) * D_ + c];
      b1p[c] = acc;
    }
  } else if (tid < 2688 + 16384) {
    int i = tid - 2688;
    int n = i >> 7, k = i & 127;
    float acc = 0.f;
    for (int m = 0; m < D_; ++m) acc += W2[k * D_ + m] * Wu[m * D_ + n];
    W2uT[i] = f2bf(acc);
  } else if (tid < 19072 + 128) {
    int n = tid - 19072;
    float acc = 0.f;
    for (int m = 0; m < D_; ++m) acc += b2[m] * Wu[m * D_ + n];
    c2[n] = acc;
  } else if (tid < 19200 + 32768) {
    int i = tid - 19200;
    int r = i >> 7, k = i & 127;
    int half = r >> 7, n = r & 127;
    W1T[i] = f2bf(W1[(size_t)(half * 128 + k) * D_ + n]);
  }
}

// ---------------------------------------------------------------------------
// MFMA pq: P = edge_attr @ W1[0:128], Q = edge_attr @ W1[128:256], bf16 out.
__global__ __launch_bounds__(256) void pq_mfma(const float* __restrict__ edge_attr,
                                               const unsigned short* __restrict__ W1T,
                                               unsigned short* __restrict__ P,
                                               unsigned short* __restrict__ Q, int E) {
  const int lane = threadIdx.x & 63;
  const int wave = threadIdx.x >> 6;
  const int e0 = (blockIdx.x * 4 + wave) * 16;
  if (e0 >= E) return;
  const int row = lane & 15;
  const int quad = lane >> 4;
  int e = e0 + row; if (e >= E) e = E - 1;

  union { bf16x8 v; unsigned short u[8]; } afr[4];
  const float* arow = edge_attr + (size_t)e * D_ + quad * 8;
#pragma unroll
  for (int kt = 0; kt < 4; ++kt) {
    float4 f0 = *(const float4*)(arow + kt * 32);
    float4 f1 = *(const float4*)(arow + kt * 32 + 4);
    afr[kt].u[0] = f2bf(f0.x); afr[kt].u[1] = f2bf(f0.y);
    afr[kt].u[2] = f2bf(f0.z); afr[kt].u[3] = f2bf(f0.w);
    afr[kt].u[4] = f2bf(f1.x); afr[kt].u[5] = f2bf(f1.y);
    afr[kt].u[6] = f2bf(f1.z); afr[kt].u[7] = f2bf(f1.w);
  }
#pragma unroll
  for (int half = 0; half < 2; ++half) {
    unsigned short* Obase = half ? Q : P;
#pragma unroll
    for (int nt = 0; nt < 8; ++nt) {
      const unsigned short* wrow =
          W1T + ((size_t)(half * 128 + nt * 16 + row)) * 128 + quad * 8;
      f32x4 acc = {0.f, 0.f, 0.f, 0.f};
#pragma unroll
      for (int kt = 0; kt < 4; ++kt) {
        bf16x8 bfr = *(const bf16x8*)(wrow + kt * 32);
        acc = __builtin_amdgcn_mfma_f32_16x16x32_bf16(afr[kt].v, bfr, acc, 0, 0, 0);
      }
      int n = nt * 16 + row;
#pragma unroll
      for (int i = 0; i < 4; ++i) {
        int er = e0 + quad * 4 + i;
        if (er < E) Obase[(size_t)er * D_ + n] = f2bf(acc[i]);
      }
    }
  }
}

// ---------------------------------------------------------------------------
// Counting sort by e_ij
__global__ void hist_kernel(const int* __restrict__ tbe, int* __restrict__ cnt, int T_) {
  int t = blockIdx.x * blockDim.x + threadIdx.x;
  if (t < T_) atomicAdd(&cnt[((const int2*)tbe)[t].x], 1);
}

__global__ __launch_bounds__(SCAN_B) void scan1_kernel(const int* __restrict__ cnt,
                                                       int* __restrict__ pre,
                                                       int* __restrict__ bsum, int E) {
  __shared__ int lds[SCAN_B];
  int tid = threadIdx.x, i = blockIdx.x * SCAN_B + tid;
  int v = (i < E) ? cnt[i] : 0;
  lds[tid] = v;
  __syncthreads();
  for (int d = 1; d < SCAN_B; d <<= 1) {
    int add = (tid >= d) ? lds[tid - d] : 0;
    __syncthreads();
    lds[tid] += add;
    __syncthreads();
  }
  if (i < E) pre[i] = lds[tid] - v;
  if (tid == SCAN_B - 1) bsum[blockIdx.x] = lds[tid];
}

__global__ void scan2_kernel(int* __restrict__ bsum, int nb) {
  __shared__ int lds[256];
  int tid = threadIdx.x;
  int v = (tid < nb) ? bsum[tid] : 0;
  lds[tid] = v;
  __syncthreads();
  for (int d = 1; d < 256; d <<= 1) {
    int add = (tid >= d) ? lds[tid - d] : 0;
    __syncthreads();
    lds[tid] += add;
    __syncthreads();
  }
  if (tid < nb) bsum[tid] = lds[tid] - v;
}

__global__ __launch_bounds__(SCAN_B) void scan3_kernel(const int* __restrict__ pre,
                                                       const int* __restrict__ bsum,
                                                       int* __restrict__ offs,
                                                       int* __restrict__ cursor, int E, int T_) {
  int i = blockIdx.x * SCAN_B + threadIdx.x;
  if (i < E) {
    int o = pre[i] + bsum[blockIdx.x];
    offs[i] = o;
    cursor[i] = o;
  }
  if (i == 0) offs[E] = T_;
}

// Scatter + fused geometry: writes seik[pos] and g[pos][20] (fp32, float4 x5).
__global__ void scatter_kernel(const int* __restrict__ tbe, int* __restrict__ cursor,
                               const float* __restrict__ edge_vectors,
                               const float* __restrict__ A1, const float* __restrict__ ab1,
                               int* __restrict__ seik, float* __restrict__ gT, int T_) {
  int t = blockIdx.x * blockDim.x + threadIdx.x;
  if (t >= T_) return;
  int2 v = ((const int2*)tbe)[t];
  int pos = atomicAdd(&cursor[v.x], 1);
  seik[pos] = v.y;
  const float* vj = edge_vectors + 3 * (size_t)v.x;
  const float* vk = edge_vectors + 3 * (size_t)v.y;
  float jx = vj[0], jy = vj[1], jz = vj[2];
  float kx = vk[0], ky = vk[1], kz = vk[2];
  float lij = fmaxf(sqrtf(jx * jx + jy * jy + jz * jz), 1e-6f);
  float lik = fmaxf(sqrtf(kx * kx + ky * ky + kz * kz), 1e-6f);
  float cosv = (jx * kx + jy * ky + jz * kz) / (lij * lik);
  cosv = fminf(fmaxf(cosv, -1.f), 1.f);
  union { float4 v4[5]; float f[NB_]; } gr;
#pragma unroll
  for (int k = 0; k < NB_; ++k)
    gr.f[k] = silu_f(lij * A1[k] + lik * A1[NB_ + k] + cosv * A1[2 * NB_ + k] + ab1[k]);
  float4* gp = (float4*)(gT + (size_t)pos * NB_);
#pragma unroll
  for (int i = 0; i < 5; ++i) gp[i] = gr.v4[i];
}

// ---------------------------------------------------------------------------
// One wave per edge segment, software-pipelined:
//   s[e] = sum_t silu(P[e] + Q[eik_t] + g_t@M + b1p)
__global__ __launch_bounds__(256) void seg_kernel(
    const int* __restrict__ offs, const int* __restrict__ seik,
    const float* __restrict__ gT,
    const float* __restrict__ Mfold, const float* __restrict__ b1p,
    const unsigned short* __restrict__ P, const unsigned short* __restrict__ Q,
    float* __restrict__ s_out, int E) {
  const int lane = threadIdx.x & 63;
  const int wid = (blockIdx.x * blockDim.x + threadIdx.x) >> 6;
  const int nw = (gridDim.x * blockDim.x) >> 6;

  f32x2 m[NB_];
#pragma unroll
  for (int k = 0; k < NB_; ++k) {
    float2 t2 = *(const float2*)(Mfold + k * D_ + 2 * lane);
    m[k] = (f32x2){t2.x, t2.y};
  }
  const float2 bbt = *(const float2*)(b1p + 2 * lane);
  const f32x2 bb = (f32x2){bbt.x, bbt.y};

  int e = wid;
  if (e >= E) return;
  int o0 = offs[e], o1 = offs[e + 1];
  ushort2 pp = *(const ushort2*)(P + (size_t)e * D_ + 2 * lane);

  for (; e < E; e += nw) {
    // prefetch next segment's metadata + P row
    const int en = e + nw;
    int o0n = 0, o1n = 0;
    ushort2 ppn = make_ushort2(0, 0);
    if (en < E) {
      o0n = offs[en]; o1n = offs[en + 1];
      ppn = *(const ushort2*)(P + (size_t)en * D_ + 2 * lane);
    }
    f32x2 acc = (f32x2){0.f, 0.f};
    if (o1 > o0) {
      const f32x2 base = (f32x2){bf2f(pp.x), bf2f(pp.y)} + bb;
      const int t1 = (o0 + 1 < o1) ? o0 + 1 : o1 - 1;
      int eik_a = seik[o0];
      int eik_b = seik[t1];
      ushort2 qq_a = *(const ushort2*)(Q + (size_t)eik_a * D_ + 2 * lane);
      for (int t = o0; t < o1; ++t) {
        const int t2i = (t + 2 < o1) ? t + 2 : o1 - 1;
        int eik_c = seik[t2i];
        ushort2 qq_b = *(const ushort2*)(Q + (size_t)eik_b * D_ + 2 * lane);
        const int tu = __builtin_amdgcn_readfirstlane(t);
        const float4* gp = (const float4*)(gT + (size_t)tu * NB_);
        union { float4 v4[5]; float f[NB_]; } G;
#pragma unroll
        for (int i = 0; i < 5; ++i) G.v4[i] = gp[i];
        f32x2 u = base + (f32x2){bf2f(qq_a.x), bf2f(qq_a.y)};
        f32x2 ub = (f32x2){0.f, 0.f};
#pragma unroll
        for (int k = 0; k < NB_; k += 2) {
          u  += fsplat(G.f[k])     * m[k];
          ub += fsplat(G.f[k + 1]) * m[k + 1];
        }
        u += ub;
        acc += silu2(u);
        qq_a = qq_b;
        eik_b = eik_c;
      }
    }
    *(f32x2*)(s_out + (size_t)e * D_ + 2 * lane) = acc;
    o0 = o0n; o1 = o1n; pp = ppn;
  }
}

// ---------------------------------------------------------------------------
// In-place MFMA: out[e] = s[e] @ W2u + cnt[e]*c2 + bu
__global__ __launch_bounds__(256) void out_mfma(float* __restrict__ io,
                                                const unsigned short* __restrict__ W2uT,
                                                const float* __restrict__ c2,
                                                const float* __restrict__ bu,
                                                const int* __restrict__ cnt, int E) {
  const int lane = threadIdx.x & 63;
  const int wave = threadIdx.x >> 6;
  const int e0 = (blockIdx.x * 4 + wave) * 16;
  if (e0 >= E) return;
  const int row = lane & 15;
  const int quad = lane >> 4;
  int e = e0 + row; if (e >= E) e = E - 1;

  union { bf16x8 v; unsigned short u[8]; } afr[4];
  const float* arow = io + (size_t)e * D_ + quad * 8;
#pragma unroll
  for (int kt = 0; kt < 4; ++kt) {
    float4 f0 = *(const float4*)(arow + kt * 32);
    float4 f1 = *(const float4*)(arow + kt * 32 + 4);
    afr[kt].u[0] = f2bf(f0.x); afr[kt].u[1] = f2bf(f0.y);
    afr[kt].u[2] = f2bf(f0.z); afr[kt].u[3] = f2bf(f0.w);
    afr[kt].u[4] = f2bf(f1.x); afr[kt].u[5] = f2bf(f1.y);
    afr[kt].u[6] = f2bf(f1.z); afr[kt].u[7] = f2bf(f1.w);
  }
  float nf[4];
#pragma unroll
  for (int i = 0; i < 4; ++i) {
    int er = e0 + quad * 4 + i;
    nf[i] = (float)cnt[(er < E) ? er : (E - 1)];
  }
#pragma unroll
  for (int nt = 0; nt < 8; ++nt) {
    const unsigned short* wrow = W2uT + ((size_t)(nt * 16 + row)) * 128 + quad * 8;
    f32x4 acc = {0.f, 0.f, 0.f, 0.f};
#pragma unroll
    for (int kt = 0; kt < 4; ++kt) {
      bf16x8 bfr = *(const bf16x8*)(wrow + kt * 32);
      acc = __builtin_amdgcn_mfma_f32_16x16x32_bf16(afr[kt].v, bfr, acc, 0, 0, 0);
    }
    int n = nt * 16 + row;
    float c2n = c2[n], bun = bu[n];
#pragma unroll
    for (int i = 0; i < 4; ++i) {
      int er = e0 + quad * 4 + i;
      if (er < E) io[(size_t)er * D_ + n] = acc[i] + nf[i] * c2n + bun;
    }
  }
}

// ---------------------------------------------------------------------------
extern "C" void kernel_launch(void* const* d_in, const int* in_sizes, int n_in,
                              void* d_out, int out_size, void* d_ws, size_t ws_size,
                              hipStream_t stream) {
  const float* edge_attr    = (const float*)d_in[0];
  const int*   tbe          = (const int*)d_in[2];
  const float* edge_vectors = (const float*)d_in[3];
  const float* A1  = (const float*)d_in[4];
  const float* ab1 = (const float*)d_in[5];
  const float* A2  = (const float*)d_in[6];
  const float* ab2 = (const float*)d_in[7];
  const float* W1  = (const float*)d_in[8];
  const float* b1  = (const float*)d_in[9];
  const float* W2  = (const float*)d_in[10];
  const float* b2  = (const float*)d_in[11];
  const float* Wu  = (const float*)d_in[12];
  const float* bu  = (const float*)d_in[13];
  const int E = in_sizes[0] / D_;
  const int T = in_sizes[2] / 2;
  float* out = (float*)d_out;

  char* w = (char*)d_ws;
  auto carve = [&](size_t bytes) -> char* {
    char* p = w;
    w += (bytes + 255) & ~(size_t)255;
    return p;
  };
  unsigned short* P = (unsigned short*)carve((size_t)E * D_ * 2);
  unsigned short* Q = (unsigned short*)carve((size_t)E * D_ * 2);
  float* gT   = (float*)carve((size_t)T * NB_ * 4);
  int* seik   = (int*)carve((size_t)T * 4);
  int* cnt    = (int*)carve((size_t)E * 4);
  int* pre    = (int*)carve((size_t)E * 4);
  int* offs   = (int*)carve((size_t)(E + 1) * 4);
  int* cursor = (int*)carve((size_t)E * 4);
  int* bsum   = (int*)carve(1024 * 4);
  float* Mfold = (float*)carve(NB_ * D_ * 4);
  float* b1p   = (float*)carve(D_ * 4);
  unsigned short* W2uT = (unsigned short*)carve(D_ * D_ * 2);
  float* c2    = (float*)carve(D_ * 4);
  unsigned short* W1T = (unsigned short*)carve(256 * 128 * 2);

  const int nb_scan = (E + SCAN_B - 1) / SCAN_B;

  hipMemsetAsync(cnt, 0, (size_t)E * 4, stream);

  prep_kernel<<<(51968 + 255) / 256, 256, 0, stream>>>(A2, ab2, W1, b1, W2, Wu, b2,
                                                       Mfold, b1p, W2uT, c2, W1T);
  pq_mfma<<<(E + 63) / 64, 256, 0, stream>>>(edge_attr, W1T, P, Q, E);

  hist_kernel<<<(T + 255) / 256, 256, 0, stream>>>(tbe, cnt, T);
  scan1_kernel<<<nb_scan, SCAN_B, 0, stream>>>(cnt, pre, bsum, E);
  scan2_kernel<<<1, 256, 0, stream>>>(bsum, nb_scan);
  scan3_kernel<<<nb_scan, SCAN_B, 0, stream>>>(pre, bsum, offs, cursor, E, T);
  scatter_kernel<<<(T + 255) / 256, 256, 0, stream>>>(tbe, cursor, edge_vectors,
                                                      A1, ab1, seik, gT, T);

  seg_kernel<<<2048, 256, 0, stream>>>(offs, seik, gT, Mfold, b1p, P, Q, out, E);
  out_mfma<<<(E + 63) / 64, 256, 0, stream>>>(out, W2uT, c2, bu, cnt, E);
}